// Round 9
// baseline (2381.947 us; speedup 1.0000x reference)
//
#include <hip/hip_runtime.h>

#define NL 50000
#define NS 128
#define G 160
#define GSQ (160*160)
#define GCUBE (160*160*160)
#define NRB 49          // ray blocks of 1024
#define NBIN (G*3*NRB)  // 23520 count bins, plane-major: p*147 + pass*49 + rb
#define ENT_CAP 11500000

struct RayParam { float4 a, b; };  // a={A,B,AR,BR}  b={AC,BC,cb,pad}

__device__ __forceinline__ void lds_add(float* p, float v) {
    __hip_atomic_fetch_add(p, v, __ATOMIC_RELAXED, __HIP_MEMORY_SCOPE_WORKGROUP);
}

__device__ __forceinline__ float frcp(float x) {
#if __has_builtin(__builtin_amdgcn_rcpf)
    return __builtin_amdgcn_rcpf(x);
#else
    return 1.0f / x;
#endif
}

// f -> (base index, frac weight); identical math to reference.
__device__ __forceinline__ void coordf(float pos, int& i, float& w) {
    float f = (pos + 100.0f) * 0.8f - 0.5f;
    f = fminf(fmaxf(f, 0.0f), 159.0f);
    int ii = (int)f; ii = ii > 158 ? 158 : ii;
    i = ii; w = f - (float)ii;
}

// Canonical padded sample-window count for (ray slab-line f=A+B*t, plane p).
// MUST be used identically by bin_count and bin_write. bp's fa>=0 recheck
// filters the padding, so only K1==K3 consistency and over-inclusion matter.
__device__ __forceinline__ int cnt_for(float A, float B, float rB, int p, int& slo_out) {
    const float glo = (p <= 1)   ? -1.0f  : (float)(p - 1);
    const float ghi = (p >= 158) ? 160.0f : (float)(p + 1);
    int slo, shi;
    if (B == 0.0f) {
        if (A < glo || A > ghi) { slo_out = 0; return 0; }
        slo = 0; shi = NS - 1;
    } else {
        const float t1 = (glo - A) * rB, t2 = (ghi - A) * rB;
        const float tlo = fminf(t1, t2), thi = fmaxf(t1, t2);
        float slof = ceilf (tlo * (float)NS - 0.75f);
        float shif = floorf(thi * (float)NS - 0.25f);
        slof = fminf(fmaxf(slof,  0.0f), 127.0f);
        shif = fminf(fmaxf(shif, -1.0f), 127.0f);
        slo = (int)slof; shi = (int)shif;
    }
    slo_out = slo;
    return shi - slo + 1;   // may be <= 0
}

// Covered-plane range for a ray (conservative superset of {p: cnt_for>0}).
__device__ __forceinline__ void plane_range(float A, float B, int& plo, int& phi) {
    const float f0 = A + B * (0.5f / NS);
    const float f1 = A + B * (((float)NS - 0.5f) / NS);
    const float fmn = fminf(f0, f1), fmx = fmaxf(f0, f1);
    plo = (int)fmaxf(ceilf (fmn - 1.01f), 0.0f);
    phi = (int)fminf(floorf(fmx + 1.01f), 159.0f);
}

// ---------------- Stage 1: projection (gather) + param packing ----------------
template<int PA, int PB, int PC, int QS, int QR, int QC>
__device__ __forceinline__ void proj_body(
    const float* __restrict__ img,
    const float* __restrict__ lors,
    float* __restrict__ contrib,
    RayParam* __restrict__ params,
    int sa, int sb, int bx)
{
    const int wave = threadIdx.x >> 6;
    const int lane = threadIdx.x & 63;
    const int lor  = bx * 4 + wave;

    const float p1x = lors[0*NL + lor];
    const float p1y = lors[1*NL + lor];
    const float p1z = lors[2*NL + lor];
    const float dxv = lors[3*NL + lor] - p1x;
    const float dyv = lors[4*NL + lor] - p1y;
    const float dzv = lors[5*NL + lor] - p1z;
    const float len  = sqrtf(dxv*dxv + dyv*dyv + dzv*dzv);
    const float step = len * (1.0f/NS);

    float sum = 0.0f;
    #pragma unroll
    for (int q = 0; q < 2; ++q) {
        const int s = lane + q*64;
        const float t = ((float)s + 0.5f) * (1.0f/NS);
        const float pos[3] = { p1x + t*dxv, p1y + t*dyv, p1z + t*dzv };
        int ia, ib, ic; float wa, wb, wc;
        coordf(pos[PA], ia, wa);
        coordf(pos[PB], ib, wb);
        coordf(pos[PC], ic, wc);
        const float* g = img + ia*sa + ib*sb + ic;
        const float v000 = g[0],       v001 = g[1];
        const float v010 = g[sb],      v011 = g[sb + 1];
        const float v100 = g[sa],      v101 = g[sa + 1];
        const float v110 = g[sa + sb], v111 = g[sa + sb + 1];
        const float c00 = v000 + wc*(v001 - v000);
        const float c01 = v010 + wc*(v011 - v010);
        const float c10 = v100 + wc*(v101 - v100);
        const float c11 = v110 + wc*(v111 - v110);
        const float c0  = c00 + wb*(c01 - c00);
        const float c1  = c10 + wb*(c11 - c10);
        sum += c0 + wa*(c1 - c0);
    }

    #pragma unroll
    for (int off = 32; off > 0; off >>= 1)
        sum += __shfl_xor(sum, off, 64);

    if (lane == 0) {
        const float cb = 9.0f * step * step * sum;   // KW*(KW*step*sum)*step
        contrib[lor] = cb;
        if (params) {
            const float P1v[3] = { p1x, p1y, p1z };
            const float DVv[3] = { dxv, dyv, dzv };
            float4 a, b;
            a.x = (P1v[QS] + 100.0f)*0.8f - 0.5f;  a.y = DVv[QS]*0.8f;
            a.z = (P1v[QR] + 100.0f)*0.8f - 0.5f;  a.w = DVv[QR]*0.8f;
            b.x = (P1v[QC] + 100.0f)*0.8f - 0.5f;  b.y = DVv[QC]*0.8f;
            b.z = cb;                               b.w = 0.0f;
            params[lor].a = a;
            params[lor].b = b;
        }
    }
}

__global__ __launch_bounds__(256) void proj_all(
    const float* __restrict__ img,
    const float* __restrict__ xl, const float* __restrict__ yl,
    const float* __restrict__ zl,
    float* __restrict__ cz, float* __restrict__ cx, float* __restrict__ cy,
    RayParam* __restrict__ params)
{
    const int bx = blockIdx.x;
    // pass 0 = z: base = i0*GSQ + i1*G + i2 -> slab=pos0,row=pos1,col=pos2
    if (blockIdx.y == 0)
        proj_body<0,1,2, 0,1,2>(img, zl, cz, params ? params        : nullptr, GSQ, G, bx);
    // pass 1 = x: base = i1*GSQ + i2*G + i0 -> slab=pos1,row=pos2,col=pos0
    else if (blockIdx.y == 1)
        proj_body<1,2,0, 1,2,0>(img, xl, cx, params ? params +   NL : nullptr, GSQ, G, bx);
    // pass 2 = y: base = i1*GSQ + i0*G + i2 -> slab=pos1,row=pos0,col=pos2
    else
        proj_body<0,1,2, 1,0,2>(img, yl, cy, params ? params + 2*NL : nullptr, G, GSQ, bx);
}

// ---------------- K1: per-(plane,pass,rayblock) entry counts ----------------
__global__ __launch_bounds__(256) void bin_count(
    const RayParam* __restrict__ params, int* __restrict__ counts)
{
    const int rb = blockIdx.x, pass = blockIdx.y;
    __shared__ int cnt[G];
    for (int i = threadIdx.x; i < G; i += 256) cnt[i] = 0;
    __syncthreads();

    #pragma unroll
    for (int q = 0; q < 4; ++q) {
        const int r = rb*1024 + q*256 + threadIdx.x;
        if (r < NL) {
            const float2 ab = *(const float2*)&params[pass*NL + r].a;
            const float A = ab.x, B = ab.y;
            int plo, phi; plane_range(A, B, plo, phi);
            const float rB = frcp(B);
            for (int p = plo; p <= phi; ++p) {
                int slo; const int c = cnt_for(A, B, rB, p, slo);
                if (c > 0) atomicAdd(&cnt[p], (c + 7) >> 3);
            }
        }
    }
    __syncthreads();
    for (int i = threadIdx.x; i < G; i += 256)
        counts[i*(3*NRB) + pass*NRB + rb] = cnt[i];
}

// ---------------- K2: exclusive scan of 23520 counts (one WG) ----------------
#define SCAN_PT 23   // 1024*23 = 23552 >= NBIN
__global__ __launch_bounds__(1024) void scan_offsets(
    const int* __restrict__ counts, int* __restrict__ offsets)
{
    __shared__ int lsum[1024];
    const int tid = threadIdx.x;
    int s = 0;
    #pragma unroll
    for (int j = 0; j < SCAN_PT; ++j) {
        const int idx = tid*SCAN_PT + j;
        if (idx < NBIN) s += counts[idx];
    }
    lsum[tid] = s;
    __syncthreads();
    for (int off = 1; off < 1024; off <<= 1) {
        const int v = (tid >= off) ? lsum[tid - off] : 0;
        __syncthreads();
        lsum[tid] += v;
        __syncthreads();
    }
    int running = lsum[tid] - s;   // exclusive start
    #pragma unroll
    for (int j = 0; j < SCAN_PT; ++j) {
        const int idx = tid*SCAN_PT + j;
        if (idx < NBIN) { offsets[idx] = running; running += counts[idx]; }
    }
    if (tid == 1023) offsets[NBIN] = lsum[1023];
}

// ---------------- K3: write entries at deterministic slots ----------------
// entry u32: ray[0:17) | s0[17:24) | (n-1)[24:27) | pass[27:29)
__global__ __launch_bounds__(256) void bin_write(
    const RayParam* __restrict__ params, const int* __restrict__ offsets,
    unsigned* __restrict__ entries)
{
    const int rb = blockIdx.x, pass = blockIdx.y;
    __shared__ int cur[G];
    for (int i = threadIdx.x; i < G; i += 256)
        cur[i] = offsets[i*(3*NRB) + pass*NRB + rb];
    __syncthreads();

    #pragma unroll
    for (int q = 0; q < 4; ++q) {
        const int r = rb*1024 + q*256 + threadIdx.x;
        if (r < NL) {
            const float2 ab = *(const float2*)&params[pass*NL + r].a;
            const float A = ab.x, B = ab.y;
            int plo, phi; plane_range(A, B, plo, phi);
            const float rB = frcp(B);
            for (int p = plo; p <= phi; ++p) {
                int slo; const int c = cnt_for(A, B, rB, p, slo);
                if (c > 0) {
                    const int ke = (c + 7) >> 3;
                    const int base = atomicAdd(&cur[p], ke);
                    for (int e = 0; e < ke; ++e) {
                        const int s0 = slo + e*8;
                        const int n  = (c - e*8) < 8 ? (c - e*8) : 8;
                        const unsigned enc = (unsigned)r | ((unsigned)s0 << 17)
                                           | ((unsigned)(n-1) << 24)
                                           | ((unsigned)pass << 27);
                        if (base + e < ENT_CAP) entries[base + e] = enc;
                    }
                }
            }
        }
    }
}

// ---------------- bp over binned entries: one WG per output plane ----------------
__global__ __launch_bounds__(1024) void bp_binned(
    const RayParam* __restrict__ params, const int* __restrict__ offsets,
    const unsigned* __restrict__ entries,
    const float* __restrict__ img, const float* __restrict__ eff,
    float* __restrict__ out)
{
    __shared__ float plane[GSQ];
    const int p   = blockIdx.x;
    const int tid = threadIdx.x;

    for (int j = tid; j < GSQ; j += 1024) plane[j] = 0.0f;
    __syncthreads();

    const int start = offsets[p*(3*NRB)];
    int end = offsets[(p+1)*(3*NRB)];
    if (end > ENT_CAP) end = ENT_CAP;

    for (int e = start + tid; e < end; e += 1024) {
        const unsigned enc = entries[e];
        const int r    = enc & 0x1FFFF;
        const int s0   = (enc >> 17) & 0x7F;
        const int n    = ((enc >> 24) & 0x7) + 1;
        const int pass = enc >> 27;
        const RayParam rp = params[pass*NL + r];
        const float A = rp.a.x, B = rp.a.y, AR = rp.a.z, BR = rp.a.w;
        const float AC = rp.b.x, BC = rp.b.y, cb = rp.b.z;
        for (int i = 0; i < n; ++i) {
            const float t = ((float)(s0 + i) + 0.5f) * (1.0f/NS);
            float fA = A + B*t;
            fA = fminf(fmaxf(fA, 0.0f), 159.0f);
            int ia = (int)fA; ia = ia > 158 ? 158 : ia;
            const float wa = fA - (float)ia;
            float fa;
            if (ia == p)          fa = 1.0f - wa;
            else if (ia == p - 1) fa = wa;
            else                  fa = -1.0f;
            if (fa >= 0.0f) {
                float fR = AR + BR*t, fC = AC + BC*t;
                fR = fminf(fmaxf(fR, 0.0f), 159.0f);
                fC = fminf(fmaxf(fC, 0.0f), 159.0f);
                int ib = (int)fR; ib = ib > 158 ? 158 : ib;
                int ic = (int)fC; ic = ic > 158 ? 158 : ic;
                const float wb = fR - (float)ib;
                const float wc = fC - (float)ic;
                const float v  = fa * cb;
                const float v0 = v * (1.0f - wb), v1 = v * wb;
                float* q = plane + ib*G + ic;
                lds_add(q,         v0 * (1.0f - wc));
                lds_add(q + 1,     v0 * wc);
                lds_add(q + G,     v1 * (1.0f - wc));
                lds_add(q + G + 1, v1 * wc);
            }
        }
    }
    __syncthreads();

    const int pbase = p * GSQ;
    for (int j = tid; j < GSQ; j += 1024) {
        const int idx = pbase + j;
        out[idx] = plane[j] * img[idx] * eff[idx];
    }
}

// ---------------- fallback: fused per-plane scan (round-6, proven) ----------------
template<int PS, int PR, int PC2>
__device__ __forceinline__ void slab_accum(
    float* __restrict__ plane,
    const float* __restrict__ lors,
    const float* __restrict__ contrib,
    int p, int wave, int lane, int nwaves)
{
    const float glo = (p <= 1)   ? -1.0f  : (float)(p - 1);
    const float ghi = (p >= 158) ? 160.0f : (float)(p + 1);

    for (int base = wave*64; base < NL; base += nwaves*64) {
        const int r = base + lane;
        float A = 0.f, B = 0.f, AR = 0.f, BR = 0.f, AC = 0.f, BC = 0.f, cb = 0.f;
        int slo = 0, cnt = 0;
        if (r < NL) {
            const float q0 = lors[0*NL + r], q1 = lors[1*NL + r], q2 = lors[2*NL + r];
            const float d0 = lors[3*NL + r] - q0;
            const float d1 = lors[4*NL + r] - q1;
            const float d2 = lors[5*NL + r] - q2;
            const float P1[3] = { q0, q1, q2 };
            const float DV[3] = { d0, d1, d2 };
            A  = (P1[PS]  + 100.0f)*0.8f - 0.5f;  B  = DV[PS]*0.8f;
            AR = (P1[PR]  + 100.0f)*0.8f - 0.5f;  BR = DV[PR]*0.8f;
            AC = (P1[PC2] + 100.0f)*0.8f - 0.5f;  BC = DV[PC2]*0.8f;
            cb = contrib[r];
            const float rB = frcp(B);
            cnt = cnt_for(A, B, rB, p, slo);
            if (cnt < 0) cnt = 0;
        }

        int pref = cnt;
        #pragma unroll
        for (int off = 1; off < 64; off <<= 1) {
            const int n = __shfl_up(pref, off, 64);
            if (lane >= off) pref += n;
        }
        const int total = __shfl(pref, 63, 64);
        const int start = pref - cnt;

        for (int k0 = 0; k0 < total; k0 += 64) {
            const int k  = k0 + lane;
            const int kc = k < total ? k : total - 1;

            int j = 0;
            #pragma unroll
            for (int stp = 32; stp >= 1; stp >>= 1) {
                const int cand = j + stp;
                const int sc = __shfl(start, cand, 64);
                if (cand < 64 && sc <= kc) j = cand;
            }

            const int   sj  = __shfl(slo,   j, 64);
            const int   stj = __shfl(start, j, 64);
            const float Aj  = __shfl(A,  j, 64);
            const float Bj  = __shfl(B,  j, 64);
            const float ARj = __shfl(AR, j, 64);
            const float BRj = __shfl(BR, j, 64);
            const float ACj = __shfl(AC, j, 64);
            const float BCj = __shfl(BC, j, 64);
            const float cbj = __shfl(cb, j, 64);

            const int s = sj + (kc - stj);
            const float t = ((float)s + 0.5f) * (1.0f/NS);
            float fA = Aj + Bj * t;
            fA = fminf(fmaxf(fA, 0.0f), 159.0f);
            int ia = (int)fA; ia = ia > 158 ? 158 : ia;
            const float wa = fA - (float)ia;
            float fa;
            if (ia == p)          fa = 1.0f - wa;
            else if (ia == p - 1) fa = wa;
            else                  fa = -1.0f;

            float fR = ARj + BRj * t;
            float fC = ACj + BCj * t;
            fR = fminf(fmaxf(fR, 0.0f), 159.0f);
            fC = fminf(fmaxf(fC, 0.0f), 159.0f);
            int ib = (int)fR; ib = ib > 158 ? 158 : ib;
            int ic = (int)fC; ic = ic > 158 ? 158 : ic;
            const float wb = fR - (float)ib;
            const float wc = fC - (float)ic;

            if (k < total && fa >= 0.0f) {
                const float v  = fa * cbj;
                const float v0 = v * (1.0f - wb), v1 = v * wb;
                float* q = plane + ib*G + ic;
                lds_add(q,         v0 * (1.0f - wc));
                lds_add(q + 1,     v0 * wc);
                lds_add(q + G,     v1 * (1.0f - wc));
                lds_add(q + G + 1, v1 * wc);
            }
        }
    }
}

__global__ __launch_bounds__(1024) void bp_fused(
    const float* __restrict__ img, const float* __restrict__ eff,
    const float* __restrict__ zl, const float* __restrict__ xl,
    const float* __restrict__ yl,
    const float* __restrict__ cz, const float* __restrict__ cx,
    const float* __restrict__ cy,
    float* __restrict__ out)
{
    __shared__ float plane[GSQ];
    const int p    = blockIdx.x;
    const int tid  = threadIdx.x;
    const int wave = tid >> 6;
    const int lane = tid & 63;

    for (int j = tid; j < GSQ; j += 1024) plane[j] = 0.0f;
    __syncthreads();

    slab_accum<0,1,2>(plane, zl, cz, p, wave, lane, 16);
    slab_accum<1,2,0>(plane, xl, cx, p, wave, lane, 16);
    slab_accum<1,0,2>(plane, yl, cy, p, wave, lane, 16);

    __syncthreads();

    const int pbase = p * GSQ;
    for (int j = tid; j < GSQ; j += 1024) {
        const int idx = pbase + j;
        out[idx] = plane[j] * img[idx] * eff[idx];
    }
}

extern "C" void kernel_launch(void* const* d_in, const int* in_sizes, int n_in,
                              void* d_out, int out_size, void* d_ws, size_t ws_size,
                              hipStream_t stream) {
    const float* img = (const float*)d_in[0];
    const float* eff = (const float*)d_in[1];
    const float* xl  = (const float*)d_in[2];
    const float* yl  = (const float*)d_in[3];
    const float* zl  = (const float*)d_in[4];
    float* out = (float*)d_out;

    const size_t CONTRIB_B = (size_t)3*NL*sizeof(float);       //   600 KB
    const size_t PARAMS_B  = (size_t)3*NL*sizeof(RayParam);    //   4.8 MB
    const size_t COUNTS_B  = (size_t)(NBIN)*sizeof(int);       //    94 KB
    const size_t OFFS_B    = (size_t)(NBIN+1)*sizeof(int);     //    94 KB
    const size_t ENT_B     = (size_t)ENT_CAP*sizeof(unsigned); //    46 MB

    char* w = (char*)d_ws;
    float*    cz      = (float*)w;
    float*    cx      = cz + NL;
    float*    cy      = cx + NL;
    RayParam* params  = (RayParam*)(w + CONTRIB_B);
    int*      counts  = (int*)(w + CONTRIB_B + PARAMS_B);
    int*      offsets = (int*)(w + CONTRIB_B + PARAMS_B + COUNTS_B);
    unsigned* entries = (unsigned*)(w + CONTRIB_B + PARAMS_B + COUNTS_B + OFFS_B);

    const bool binned =
        ws_size >= CONTRIB_B + PARAMS_B + COUNTS_B + OFFS_B + ENT_B;  // 51.6 MB

    proj_all<<<dim3(NL/4, 3), dim3(256), 0, stream>>>(
        img, xl, yl, zl, cz, cx, cy, binned ? params : nullptr);

    if (binned) {
        bin_count   <<<dim3(NRB, 3), dim3(256),  0, stream>>>(params, counts);
        scan_offsets<<<dim3(1),      dim3(1024), 0, stream>>>(counts, offsets);
        bin_write   <<<dim3(NRB, 3), dim3(256),  0, stream>>>(params, offsets, entries);
        bp_binned   <<<dim3(G),      dim3(1024), 0, stream>>>(params, offsets, entries,
                                                              img, eff, out);
    } else {
        bp_fused<<<dim3(G), dim3(1024), 0, stream>>>(
            img, eff, zl, xl, yl, cz, cx, cy, out);
    }
}

// Round 10
// 1795.646 us; speedup vs baseline: 1.3265x; 1.3265x over previous
//
#include <hip/hip_runtime.h>

#define NL 50000
#define NS 128
#define G 160
#define GSQ (160*160)
#define GCUBE (160*160*160)
#define NRB 49          // ray blocks of 1024
#define NBIN (G*3*NRB)  // 23520 count bins, plane-major: p*147 + pass*49 + rb
#define ENT_CAP 11500000

struct RayParam { float4 a, b; };  // a={A,B,AR,BR}  b={AC,BC,cb,pad}

// Non-returning LDS f32 atomic: atomicAdd with dead result -> ds_add_f32.
// (__hip_atomic_fetch_add risked the _rtn form; suspected 4.2cyc/lane cost.)
__device__ __forceinline__ void lds_add(float* p, float v) {
    atomicAdd(p, v);
}

__device__ __forceinline__ float frcp(float x) {
#if __has_builtin(__builtin_amdgcn_rcpf)
    return __builtin_amdgcn_rcpf(x);
#else
    return 1.0f / x;
#endif
}

// f -> (base index, frac weight); identical math to reference.
__device__ __forceinline__ void coordf(float pos, int& i, float& w) {
    float f = (pos + 100.0f) * 0.8f - 0.5f;
    f = fminf(fmaxf(f, 0.0f), 159.0f);
    int ii = (int)f; ii = ii > 158 ? 158 : ii;
    i = ii; w = f - (float)ii;
}

// Canonical padded sample-window count for (ray slab-line f=A+B*t, plane p).
// MUST be used identically by bin_count and bin_write.
__device__ __forceinline__ int cnt_for(float A, float B, float rB, int p, int& slo_out) {
    const float glo = (p <= 1)   ? -1.0f  : (float)(p - 1);
    const float ghi = (p >= 158) ? 160.0f : (float)(p + 1);
    int slo, shi;
    if (B == 0.0f) {
        if (A < glo || A > ghi) { slo_out = 0; return 0; }
        slo = 0; shi = NS - 1;
    } else {
        const float t1 = (glo - A) * rB, t2 = (ghi - A) * rB;
        const float tlo = fminf(t1, t2), thi = fmaxf(t1, t2);
        float slof = ceilf (tlo * (float)NS - 0.75f);
        float shif = floorf(thi * (float)NS - 0.25f);
        slof = fminf(fmaxf(slof,  0.0f), 127.0f);
        shif = fminf(fmaxf(shif, -1.0f), 127.0f);
        slo = (int)slof; shi = (int)shif;
    }
    slo_out = slo;
    return shi - slo + 1;   // may be <= 0
}

__device__ __forceinline__ void plane_range(float A, float B, int& plo, int& phi) {
    const float f0 = A + B * (0.5f / NS);
    const float f1 = A + B * (((float)NS - 0.5f) / NS);
    const float fmn = fminf(f0, f1), fmx = fmaxf(f0, f1);
    plo = (int)fmaxf(ceilf (fmn - 1.01f), 0.0f);
    phi = (int)fminf(floorf(fmx + 1.01f), 159.0f);
}

// ---------------- Stage 1: projection (gather) + param packing ----------------
template<int PA, int PB, int PC, int QS, int QR, int QC>
__device__ __forceinline__ void proj_body(
    const float* __restrict__ img,
    const float* __restrict__ lors,
    float* __restrict__ contrib,
    RayParam* __restrict__ params,
    int sa, int sb, int bx)
{
    const int wave = threadIdx.x >> 6;
    const int lane = threadIdx.x & 63;
    const int lor  = bx * 4 + wave;

    const float p1x = lors[0*NL + lor];
    const float p1y = lors[1*NL + lor];
    const float p1z = lors[2*NL + lor];
    const float dxv = lors[3*NL + lor] - p1x;
    const float dyv = lors[4*NL + lor] - p1y;
    const float dzv = lors[5*NL + lor] - p1z;
    const float len  = sqrtf(dxv*dxv + dyv*dyv + dzv*dzv);
    const float step = len * (1.0f/NS);

    float sum = 0.0f;
    #pragma unroll
    for (int q = 0; q < 2; ++q) {
        const int s = lane + q*64;
        const float t = ((float)s + 0.5f) * (1.0f/NS);
        const float pos[3] = { p1x + t*dxv, p1y + t*dyv, p1z + t*dzv };
        int ia, ib, ic; float wa, wb, wc;
        coordf(pos[PA], ia, wa);
        coordf(pos[PB], ib, wb);
        coordf(pos[PC], ic, wc);
        const float* g = img + ia*sa + ib*sb + ic;
        const float v000 = g[0],       v001 = g[1];
        const float v010 = g[sb],      v011 = g[sb + 1];
        const float v100 = g[sa],      v101 = g[sa + 1];
        const float v110 = g[sa + sb], v111 = g[sa + sb + 1];
        const float c00 = v000 + wc*(v001 - v000);
        const float c01 = v010 + wc*(v011 - v010);
        const float c10 = v100 + wc*(v101 - v100);
        const float c11 = v110 + wc*(v111 - v110);
        const float c0  = c00 + wb*(c01 - c00);
        const float c1  = c10 + wb*(c11 - c10);
        sum += c0 + wa*(c1 - c0);
    }

    #pragma unroll
    for (int off = 32; off > 0; off >>= 1)
        sum += __shfl_xor(sum, off, 64);

    if (lane == 0) {
        const float cb = 9.0f * step * step * sum;   // KW*(KW*step*sum)*step
        contrib[lor] = cb;
        if (params) {
            const float P1v[3] = { p1x, p1y, p1z };
            const float DVv[3] = { dxv, dyv, dzv };
            float4 a, b;
            a.x = (P1v[QS] + 100.0f)*0.8f - 0.5f;  a.y = DVv[QS]*0.8f;
            a.z = (P1v[QR] + 100.0f)*0.8f - 0.5f;  a.w = DVv[QR]*0.8f;
            b.x = (P1v[QC] + 100.0f)*0.8f - 0.5f;  b.y = DVv[QC]*0.8f;
            b.z = cb;                               b.w = 0.0f;
            params[lor].a = a;
            params[lor].b = b;
        }
    }
}

__global__ __launch_bounds__(256) void proj_all(
    const float* __restrict__ img,
    const float* __restrict__ xl, const float* __restrict__ yl,
    const float* __restrict__ zl,
    float* __restrict__ cz, float* __restrict__ cx, float* __restrict__ cy,
    RayParam* __restrict__ params)
{
    const int bx = blockIdx.x;
    if (blockIdx.y == 0)
        proj_body<0,1,2, 0,1,2>(img, zl, cz, params ? params        : nullptr, GSQ, G, bx);
    else if (blockIdx.y == 1)
        proj_body<1,2,0, 1,2,0>(img, xl, cx, params ? params +   NL : nullptr, GSQ, G, bx);
    else
        proj_body<0,1,2, 1,0,2>(img, yl, cy, params ? params + 2*NL : nullptr, G, GSQ, bx);
}

// ---------------- K1: per-(plane,pass,rayblock) entry counts ----------------
__global__ __launch_bounds__(256) void bin_count(
    const RayParam* __restrict__ params, int* __restrict__ counts)
{
    const int rb = blockIdx.x, pass = blockIdx.y;
    __shared__ int cnt[G];
    for (int i = threadIdx.x; i < G; i += 256) cnt[i] = 0;
    __syncthreads();

    #pragma unroll
    for (int q = 0; q < 4; ++q) {
        const int r = rb*1024 + q*256 + threadIdx.x;
        if (r < NL) {
            const float2 ab = *(const float2*)&params[pass*NL + r].a;
            const float A = ab.x, B = ab.y;
            int plo, phi; plane_range(A, B, plo, phi);
            const float rB = frcp(B);
            for (int p = plo; p <= phi; ++p) {
                int slo; const int c = cnt_for(A, B, rB, p, slo);
                if (c > 0) atomicAdd(&cnt[p], (c + 7) >> 3);
            }
        }
    }
    __syncthreads();
    for (int i = threadIdx.x; i < G; i += 256)
        counts[i*(3*NRB) + pass*NRB + rb] = cnt[i];
}

// ---------------- K2: exclusive scan of 23520 counts (one WG) ----------------
#define SCAN_PT 23   // 1024*23 = 23552 >= NBIN
__global__ __launch_bounds__(1024) void scan_offsets(
    const int* __restrict__ counts, int* __restrict__ offsets)
{
    __shared__ int lsum[1024];
    const int tid = threadIdx.x;
    int s = 0;
    #pragma unroll
    for (int j = 0; j < SCAN_PT; ++j) {
        const int idx = tid*SCAN_PT + j;
        if (idx < NBIN) s += counts[idx];
    }
    lsum[tid] = s;
    __syncthreads();
    for (int off = 1; off < 1024; off <<= 1) {
        const int v = (tid >= off) ? lsum[tid - off] : 0;
        __syncthreads();
        lsum[tid] += v;
        __syncthreads();
    }
    int running = lsum[tid] - s;   // exclusive start
    #pragma unroll
    for (int j = 0; j < SCAN_PT; ++j) {
        const int idx = tid*SCAN_PT + j;
        if (idx < NBIN) { offsets[idx] = running; running += counts[idx]; }
    }
    if (tid == 1023) offsets[NBIN] = lsum[1023];
}

// ---------------- K3: write entries at deterministic slots ----------------
// entry u32: ray[0:17) | s0[17:24) | (n-1)[24:27) | pass[27:29)
__global__ __launch_bounds__(256) void bin_write(
    const RayParam* __restrict__ params, const int* __restrict__ offsets,
    unsigned* __restrict__ entries)
{
    const int rb = blockIdx.x, pass = blockIdx.y;
    __shared__ int cur[G];
    for (int i = threadIdx.x; i < G; i += 256)
        cur[i] = offsets[i*(3*NRB) + pass*NRB + rb];
    __syncthreads();

    #pragma unroll
    for (int q = 0; q < 4; ++q) {
        const int r = rb*1024 + q*256 + threadIdx.x;
        if (r < NL) {
            const float2 ab = *(const float2*)&params[pass*NL + r].a;
            const float A = ab.x, B = ab.y;
            int plo, phi; plane_range(A, B, plo, phi);
            const float rB = frcp(B);
            for (int p = plo; p <= phi; ++p) {
                int slo; const int c = cnt_for(A, B, rB, p, slo);
                if (c > 0) {
                    const int ke = (c + 7) >> 3;
                    const int base = atomicAdd(&cur[p], ke);
                    for (int e = 0; e < ke; ++e) {
                        const int s0 = slo + e*8;
                        const int n  = (c - e*8) < 8 ? (c - e*8) : 8;
                        const unsigned enc = (unsigned)r | ((unsigned)s0 << 17)
                                           | ((unsigned)(n-1) << 24)
                                           | ((unsigned)pass << 27);
                        if (base + e < ENT_CAP) entries[base + e] = enc;
                    }
                }
            }
        }
    }
}

// ---------------- bp over binned entries: 3 chunk-WGs per output plane ----------------
// Each WG accumulates its third of plane p's entries into a private LDS plane,
// then flushes via coalesced global atomic adds into out (raw sums).
__global__ __launch_bounds__(1024) void bp_binned3(
    const RayParam* __restrict__ params, const int* __restrict__ offsets,
    const unsigned* __restrict__ entries,
    float* __restrict__ out)
{
    __shared__ float plane[GSQ];
    const int p   = blockIdx.x;
    const int c   = blockIdx.y;      // chunk 0..2
    const int tid = threadIdx.x;

    for (int j = tid; j < GSQ; j += 1024) plane[j] = 0.0f;
    __syncthreads();

    int s0 = offsets[p*(3*NRB)];
    int e0 = offsets[(p+1)*(3*NRB)];
    if (e0 > ENT_CAP) e0 = ENT_CAP;
    if (s0 > e0) s0 = e0;
    const int n  = e0 - s0;
    const int cs = s0 + (int)(((long long)n *  c     ) / 3);
    const int ce = s0 + (int)(((long long)n * (c + 1)) / 3);

    for (int e = cs + tid; e < ce; e += 1024) {
        const unsigned enc = entries[e];
        const int r    = enc & 0x1FFFF;
        const int ss   = (enc >> 17) & 0x7F;
        const int nn   = ((enc >> 24) & 0x7) + 1;
        const int pass = enc >> 27;
        const RayParam rp = params[pass*NL + r];
        const float A = rp.a.x, B = rp.a.y, AR = rp.a.z, BR = rp.a.w;
        const float AC = rp.b.x, BC = rp.b.y, cb = rp.b.z;
        for (int i = 0; i < nn; ++i) {
            const float t = ((float)(ss + i) + 0.5f) * (1.0f/NS);
            float fA = A + B*t;
            fA = fminf(fmaxf(fA, 0.0f), 159.0f);
            int ia = (int)fA; ia = ia > 158 ? 158 : ia;
            const float wa = fA - (float)ia;
            float fa;
            if (ia == p)          fa = 1.0f - wa;
            else if (ia == p - 1) fa = wa;
            else                  fa = -1.0f;
            if (fa >= 0.0f) {
                float fR = AR + BR*t, fC = AC + BC*t;
                fR = fminf(fmaxf(fR, 0.0f), 159.0f);
                fC = fminf(fmaxf(fC, 0.0f), 159.0f);
                int ib = (int)fR; ib = ib > 158 ? 158 : ib;
                int ic = (int)fC; ic = ic > 158 ? 158 : ic;
                const float wb = fR - (float)ib;
                const float wc = fC - (float)ic;
                const float v  = fa * cb;
                const float v0 = v * (1.0f - wb), v1 = v * wb;
                float* q = plane + ib*G + ic;
                lds_add(q,         v0 * (1.0f - wc));
                lds_add(q + 1,     v0 * wc);
                lds_add(q + G,     v1 * (1.0f - wc));
                lds_add(q + G + 1, v1 * wc);
            }
        }
    }
    __syncthreads();

    // Coalesced global-atomic flush of the partial plane (out pre-zeroed).
    float* dst = out + (size_t)p * GSQ;
    for (int j = tid; j < GSQ; j += 1024) {
#if __has_builtin(__builtin_amdgcn_global_atomic_fadd_f32)
        unsafeAtomicAdd(&dst[j], plane[j]);
#else
        atomicAdd(&dst[j], plane[j]);
#endif
    }
}

// finalize: out *= img * eff (in place, after raw bp sums landed)
__global__ __launch_bounds__(256) void finalize_mul(
    const float4* __restrict__ img, const float4* __restrict__ eff,
    float4* __restrict__ out)
{
    const int i = blockIdx.x * 256 + threadIdx.x;   // over GCUBE/4
    const float4 a = img[i];
    const float4 e = eff[i];
    float4 o = out[i];
    o.x *= a.x * e.x;
    o.y *= a.y * e.y;
    o.z *= a.z * e.z;
    o.w *= a.w * e.w;
    out[i] = o;
}

// ---------------- fallback: fused per-plane scan (round-6, proven) ----------------
template<int PS, int PR, int PC2>
__device__ __forceinline__ void slab_accum(
    float* __restrict__ plane,
    const float* __restrict__ lors,
    const float* __restrict__ contrib,
    int p, int wave, int lane, int nwaves)
{
    const float glo = (p <= 1)   ? -1.0f  : (float)(p - 1);
    const float ghi = (p >= 158) ? 160.0f : (float)(p + 1);

    for (int base = wave*64; base < NL; base += nwaves*64) {
        const int r = base + lane;
        float A = 0.f, B = 0.f, AR = 0.f, BR = 0.f, AC = 0.f, BC = 0.f, cb = 0.f;
        int slo = 0, cnt = 0;
        if (r < NL) {
            const float q0 = lors[0*NL + r], q1 = lors[1*NL + r], q2 = lors[2*NL + r];
            const float d0 = lors[3*NL + r] - q0;
            const float d1 = lors[4*NL + r] - q1;
            const float d2 = lors[5*NL + r] - q2;
            const float P1[3] = { q0, q1, q2 };
            const float DV[3] = { d0, d1, d2 };
            A  = (P1[PS]  + 100.0f)*0.8f - 0.5f;  B  = DV[PS]*0.8f;
            AR = (P1[PR]  + 100.0f)*0.8f - 0.5f;  BR = DV[PR]*0.8f;
            AC = (P1[PC2] + 100.0f)*0.8f - 0.5f;  BC = DV[PC2]*0.8f;
            cb = contrib[r];
            const float rB = frcp(B);
            cnt = cnt_for(A, B, rB, p, slo);
            if (cnt < 0) cnt = 0;
        }

        int pref = cnt;
        #pragma unroll
        for (int off = 1; off < 64; off <<= 1) {
            const int n = __shfl_up(pref, off, 64);
            if (lane >= off) pref += n;
        }
        const int total = __shfl(pref, 63, 64);
        const int start = pref - cnt;

        for (int k0 = 0; k0 < total; k0 += 64) {
            const int k  = k0 + lane;
            const int kc = k < total ? k : total - 1;

            int j = 0;
            #pragma unroll
            for (int stp = 32; stp >= 1; stp >>= 1) {
                const int cand = j + stp;
                const int sc = __shfl(start, cand, 64);
                if (cand < 64 && sc <= kc) j = cand;
            }

            const int   sj  = __shfl(slo,   j, 64);
            const int   stj = __shfl(start, j, 64);
            const float Aj  = __shfl(A,  j, 64);
            const float Bj  = __shfl(B,  j, 64);
            const float ARj = __shfl(AR, j, 64);
            const float BRj = __shfl(BR, j, 64);
            const float ACj = __shfl(AC, j, 64);
            const float BCj = __shfl(BC, j, 64);
            const float cbj = __shfl(cb, j, 64);

            const int s = sj + (kc - stj);
            const float t = ((float)s + 0.5f) * (1.0f/NS);
            float fA = Aj + Bj * t;
            fA = fminf(fmaxf(fA, 0.0f), 159.0f);
            int ia = (int)fA; ia = ia > 158 ? 158 : ia;
            const float wa = fA - (float)ia;
            float fa;
            if (ia == p)          fa = 1.0f - wa;
            else if (ia == p - 1) fa = wa;
            else                  fa = -1.0f;

            float fR = ARj + BRj * t;
            float fC = ACj + BCj * t;
            fR = fminf(fmaxf(fR, 0.0f), 159.0f);
            fC = fminf(fmaxf(fC, 0.0f), 159.0f);
            int ib = (int)fR; ib = ib > 158 ? 158 : ib;
            int ic = (int)fC; ic = ic > 158 ? 158 : ic;
            const float wb = fR - (float)ib;
            const float wc = fC - (float)ic;

            if (k < total && fa >= 0.0f) {
                const float v  = fa * cbj;
                const float v0 = v * (1.0f - wb), v1 = v * wb;
                float* q = plane + ib*G + ic;
                lds_add(q,         v0 * (1.0f - wc));
                lds_add(q + 1,     v0 * wc);
                lds_add(q + G,     v1 * (1.0f - wc));
                lds_add(q + G + 1, v1 * wc);
            }
        }
    }
}

__global__ __launch_bounds__(1024) void bp_fused(
    const float* __restrict__ img, const float* __restrict__ eff,
    const float* __restrict__ zl, const float* __restrict__ xl,
    const float* __restrict__ yl,
    const float* __restrict__ cz, const float* __restrict__ cx,
    const float* __restrict__ cy,
    float* __restrict__ out)
{
    __shared__ float plane[GSQ];
    const int p    = blockIdx.x;
    const int tid  = threadIdx.x;
    const int wave = tid >> 6;
    const int lane = tid & 63;

    for (int j = tid; j < GSQ; j += 1024) plane[j] = 0.0f;
    __syncthreads();

    slab_accum<0,1,2>(plane, zl, cz, p, wave, lane, 16);
    slab_accum<1,2,0>(plane, xl, cx, p, wave, lane, 16);
    slab_accum<1,0,2>(plane, yl, cy, p, wave, lane, 16);

    __syncthreads();

    const int pbase = p * GSQ;
    for (int j = tid; j < GSQ; j += 1024) {
        const int idx = pbase + j;
        out[idx] = plane[j] * img[idx] * eff[idx];
    }
}

extern "C" void kernel_launch(void* const* d_in, const int* in_sizes, int n_in,
                              void* d_out, int out_size, void* d_ws, size_t ws_size,
                              hipStream_t stream) {
    const float* img = (const float*)d_in[0];
    const float* eff = (const float*)d_in[1];
    const float* xl  = (const float*)d_in[2];
    const float* yl  = (const float*)d_in[3];
    const float* zl  = (const float*)d_in[4];
    float* out = (float*)d_out;

    const size_t CONTRIB_B = (size_t)3*NL*sizeof(float);       //   600 KB
    const size_t PARAMS_B  = (size_t)3*NL*sizeof(RayParam);    //   4.8 MB
    const size_t COUNTS_B  = (size_t)(NBIN)*sizeof(int);       //    94 KB
    const size_t OFFS_B    = (size_t)(NBIN+1)*sizeof(int);     //    94 KB
    const size_t ENT_B     = (size_t)ENT_CAP*sizeof(unsigned); //    46 MB

    char* w = (char*)d_ws;
    float*    cz      = (float*)w;
    float*    cx      = cz + NL;
    float*    cy      = cx + NL;
    RayParam* params  = (RayParam*)(w + CONTRIB_B);
    int*      counts  = (int*)(w + CONTRIB_B + PARAMS_B);
    int*      offsets = (int*)(w + CONTRIB_B + PARAMS_B + COUNTS_B);
    unsigned* entries = (unsigned*)(w + CONTRIB_B + PARAMS_B + COUNTS_B + OFFS_B);

    const bool binned =
        ws_size >= CONTRIB_B + PARAMS_B + COUNTS_B + OFFS_B + ENT_B;  // 51.6 MB

    proj_all<<<dim3(NL/4, 3), dim3(256), 0, stream>>>(
        img, xl, yl, zl, cz, cx, cy, binned ? params : nullptr);

    if (binned) {
        hipMemsetAsync(out, 0, (size_t)GCUBE * sizeof(float), stream);
        bin_count   <<<dim3(NRB, 3), dim3(256),  0, stream>>>(params, counts);
        scan_offsets<<<dim3(1),      dim3(1024), 0, stream>>>(counts, offsets);
        bin_write   <<<dim3(NRB, 3), dim3(256),  0, stream>>>(params, offsets, entries);
        bp_binned3  <<<dim3(G, 3),   dim3(1024), 0, stream>>>(params, offsets, entries, out);
        finalize_mul<<<dim3(GCUBE/4/256), dim3(256), 0, stream>>>(
            (const float4*)img, (const float4*)eff, (float4*)out);
    } else {
        bp_fused<<<dim3(G), dim3(1024), 0, stream>>>(
            img, eff, zl, xl, yl, cz, cx, cy, out);
    }
}